// Round 8
// baseline (1116.615 us; speedup 1.0000x reference)
//
#include <hip/hip_runtime.h>
#include <math.h>

typedef unsigned short u16;
typedef __attribute__((ext_vector_type(8))) short bf16x8;
typedef __attribute__((ext_vector_type(4))) float f32x4;
typedef __attribute__((ext_vector_type(4))) unsigned short u16x4;

#define NLAYERS 5
#define BATCH 8
#define SEQ 2048
#define CH 512
#define ROWS_TOTAL (BATCH * SEQ)   // 16384
#define HALF (SEQ / 2)             // 1024
// Q prescale folds softmax scale AND log2(e): qk's epilogue is then a bare
// v_exp_f32 (exp2). 512^-0.5 * 1.4426950408889634 :
#define QSCALE_EXP2 0.06375871529f
// exp cap in exp2 domain (= old 60.0 in e-domain).
#define EXP2_CAP 86.56f

// 128-sq dbuf core (qkv/pv/fc1/fc2): {As0,Bs0,As1,Bs1} x 16 KB = 64 KB
// -> 2 blocks/CU.
#define SMEM_U16 32768
// qk2 (A-in-regs): B double-buffer 2 x 32 KB = 64 KB -> 2 blocks/CU.
#define QK2_U16 32768

__device__ __forceinline__ u16 f2bf(float f) {
    unsigned u = __float_as_uint(f);
    u += 0x7fffu + ((u >> 16) & 1u);   // RNE (scalar fallback)
    return (u16)(u >> 16);
}

__device__ __forceinline__ unsigned pk2(float a, float b) {
    unsigned r;
    asm("v_cvt_pk_bf16_f32 %0, %1, %2" : "=v"(r) : "v"(a), "v"(b));
    return r;
}

__device__ __forceinline__ u16x4 pack4(f32x4 v) {
    union { unsigned u[2]; u16x4 o; } r;
    r.u[0] = pk2(v[0], v[1]);
    r.u[1] = pk2(v[2], v[3]);
    return r.o;
}

__device__ __forceinline__ void st16(u16* p, u16x4 v) { *(u16x4*)p = v; }
__device__ __forceinline__ void st16f(float* p, f32x4 v) { *(f32x4*)p = v; }

__device__ __forceinline__ float fexp2(float x) {
    float r;
    asm("v_exp_f32 %0, %1" : "=v"(r) : "v"(x));
    return r;
}

// 16-byte async global->LDS DMA. LDS dest = wave-uniform base + lane*16.
__device__ __forceinline__ void llds16(const u16* g, u16* l) {
    __builtin_amdgcn_global_load_lds(
        (const __attribute__((address_space(1))) unsigned int*)g,
        (__attribute__((address_space(3))) unsigned int*)l, 16, 0, 0);
}

// XCD-aware decode for M=16384 row-panel GEMMs (qkv/fc1/fc2): XCD k
// (bid&7) owns row-tiles [16k,16k+16) for all col-tiles -> per-XCD L2
// working set = A-panel 2.1 MB + W <= 1.6 MB < 4 MB.
__device__ __forceinline__ void xcd_rc(int& rt, int& ct) {
    const int n = blockIdx.x;
    const int m = n >> 3;
    rt = (n & 7) * 16 + (m & 15);
    ct = m >> 4;
}

// ---------------------------------------------------------------------------
// mm_compute: one BK=64 step of a 64x64 wave-tile (32 MFMAs). Frag layout
// (verified): A [m=lane&15][k=quad*8+j]; C/D col=lane&15, row=quad*4+reg.
// aoff/boff carry the chunk-XOR (0 bank conflicts measured).
// ---------------------------------------------------------------------------
__device__ __forceinline__ void mm_compute(const u16* As, const u16* Bs,
                                           const int aoff[2][4],
                                           const int boff[2][4],
                                           f32x4 acc[4][4])
{
#pragma unroll
    for (int h = 0; h < 2; ++h) {
        bf16x8 af[4], bfv[4];
#pragma unroll
        for (int t = 0; t < 4; ++t) af[t]  = *(const bf16x8*)&As[aoff[h][t]];
#pragma unroll
        for (int t = 0; t < 4; ++t) bfv[t] = *(const bf16x8*)&Bs[boff[h][t]];
#pragma unroll
        for (int ti = 0; ti < 4; ++ti)
#pragma unroll
            for (int tj = 0; tj < 4; ++tj)
                acc[ti][tj] = __builtin_amdgcn_mfma_f32_16x16x32_bf16(
                    af[ti], bfv[tj], acc[ti][tj], 0, 0, 0);
    }
}

// ---------------------------------------------------------------------------
// 128-sq dbuf core: 128x128 C-tile, 256 threads (4 waves, 2x2 of 64x64),
// BK=64. 2-deep double buffer, raw s_barrier + counted s_waitcnt vmcnt(8):
// next tile's 8 global_load_lds stay in flight across the barrier.
// ---------------------------------------------------------------------------
__device__ __forceinline__ void mm_issue(const u16* gA, const u16* gB,
                                         u16* lA, u16* lB, int lda, int ldb)
{
#pragma unroll
    for (int i = 0; i < 4; ++i)
        llds16(gA + (size_t)i * 32 * lda, lA + i * 2048);
#pragma unroll
    for (int i = 0; i < 4; ++i)
        llds16(gB + (size_t)i * 32 * ldb, lB + i * 2048);
}

__device__ __forceinline__ void mm_core(
    const u16* __restrict__ A, int lda,
    const u16* __restrict__ Bt, int ldb,
    int row0, int col0, int K,
    u16* SM, f32x4 acc[4][4])
{
    const int tid  = threadIdx.x;
    const int wave = tid >> 6, lane = tid & 63;
    const int wm = (wave & 1) * 64, wn = (wave >> 1) * 64;
    const int q  = lane >> 4,  ln = lane & 15;

    const int sr8 = lane >> 3;
    const int sc  = (lane & 7) ^ sr8;
    const u16* gA = A  + (size_t)(row0 + wave * 8 + sr8) * lda + sc * 8;
    const u16* gB = Bt + (size_t)(col0 + wave * 8 + sr8) * ldb + sc * 8;

    u16* const A0 = SM;
    u16* const B0 = SM + 8192;
    u16* const A1 = SM + 16384;
    u16* const B1 = SM + 24576;
    u16* const w0a = A0 + wave * 512;
    u16* const w0b = B0 + wave * 512;
    u16* const w1a = A1 + wave * 512;
    u16* const w1b = B1 + wave * 512;

    int aoff[2][4], boff[2][4];
#pragma unroll
    for (int h = 0; h < 2; ++h) {
        const int pos = (((h * 4 + q) ^ (ln & 7)) * 8);
#pragma unroll
        for (int t = 0; t < 4; ++t) {
            aoff[h][t] = (wm + t * 16 + ln) * 64 + pos;
            boff[h][t] = (wn + t * 16 + ln) * 64 + pos;
        }
    }

#pragma unroll
    for (int ti = 0; ti < 4; ++ti)
#pragma unroll
        for (int tj = 0; tj < 4; ++tj)
#pragma unroll
            for (int e = 0; e < 4; ++e) acc[ti][tj][e] = 0.f;

    mm_issue(gA, gB, w0a, w0b, lda, ldb);
    gA += 64; gB += 64;

    for (int k0 = 0; k0 < K; k0 += 128) {
        if (k0 + 64 < K) {
            mm_issue(gA, gB, w1a, w1b, lda, ldb);
            gA += 64; gB += 64;
            asm volatile("s_waitcnt vmcnt(8)" ::: "memory");
        } else {
            asm volatile("s_waitcnt vmcnt(0)" ::: "memory");
        }
        __builtin_amdgcn_s_barrier();
        mm_compute(A0, B0, aoff, boff, acc);
        __builtin_amdgcn_s_barrier();
        __builtin_amdgcn_sched_barrier(0);
        if (k0 + 128 < K) {
            mm_issue(gA, gB, w0a, w0b, lda, ldb);
            gA += 64; gB += 64;
            asm volatile("s_waitcnt vmcnt(8)" ::: "memory");
        } else {
            asm volatile("s_waitcnt vmcnt(0)" ::: "memory");
        }
        __builtin_amdgcn_s_barrier();
        mm_compute(A1, B1, aoff, boff, acc);
        __builtin_amdgcn_s_barrier();
        __builtin_amdgcn_sched_barrier(0);
    }
}

// Epilogue transpose (128-sq core), 4 passes of 32 rows, eb 32x132 fp32
// (132 == 4 mod 32, conflict-free).
template <typename F>
__device__ __forceinline__ void epi_emit(f32x4 acc[4][4], float* eb, F emit)
{
    const int tid = threadIdx.x, wave = tid >> 6, lane = tid & 63;
    const int wn = (wave >> 1) * 64;
    const int q = lane >> 4, ln = lane & 15;
#pragma unroll
    for (int p = 0; p < 4; ++p) {
        __syncthreads();
        if ((wave & 1) == (p >> 1)) {
            const int tibase = (p & 1) * 2;
#pragma unroll
            for (int tj = 0; tj < 4; ++tj)
#pragma unroll
                for (int t2 = 0; t2 < 2; ++t2)
#pragma unroll
                    for (int r = 0; r < 4; ++r)
                        eb[(t2 * 16 + q * 4 + r) * 132 + wn + tj * 16 + ln] =
                            acc[tibase + t2][tj][r];
        }
        __syncthreads();
#pragma unroll
        for (int s = 0; s < 4; ++s) {
            const int row = s * 8 + (tid >> 5);        // 0..31
            const int col = (tid & 31) * 4;
            f32x4 v = *(const f32x4*)&eb[row * 132 + col];
            emit(p * 32 + row, col, v);
        }
    }
}

// ---------------------------------------------------------------------------
// QKV GEMM: A=xb[16384][512], Bt=qkv_wt[1536][512]. 1-D grid (128*12),
// row-panel XCD swizzle. Q (pre-scaled by QSCALE_EXP2) and K use the
// vectorized epi; V region (ct>=8) keeps the direct acc path (transposed
// store Vt[b][c][j]). ct==0 blocks also zero rowsum.
// ---------------------------------------------------------------------------
__global__ __launch_bounds__(256) void qkv_gemm(
    const u16* __restrict__ A, const u16* __restrict__ Bt,
    const float* __restrict__ bias,
    u16* __restrict__ Qb, u16* __restrict__ Kb, u16* __restrict__ Vt,
    float* __restrict__ rowsum)
{
    __shared__ __align__(16) u16 SMEM[SMEM_U16];
    f32x4 acc[4][4];
    int rt, ct; xcd_rc(rt, ct);
    const int row0 = rt * 128, col0 = ct * 128;
    if (ct == 0 && threadIdx.x < 128)
        rowsum[row0 + threadIdx.x] = 0.f;
    mm_core(A, CH, Bt, CH, row0, col0, CH, SMEM, acc);

    if (ct < 8) {   // Q or K region (block-uniform)
        u16* dst = (ct < 4) ? Qb : Kb;
        const int cbase = (ct < 4) ? col0 : col0 - CH;
        const float sc = (ct < 4) ? QSCALE_EXP2 : 1.0f;
        epi_emit(acc, (float*)SMEM, [&](int row, int col, f32x4 v) {
            const float4 bb = *(const float4*)&bias[col0 + col];
            v[0] = (v[0] + bb.x) * sc; v[1] = (v[1] + bb.y) * sc;
            v[2] = (v[2] + bb.z) * sc; v[3] = (v[3] + bb.w) * sc;
            st16(&dst[(size_t)(row0 + row) * CH + cbase + col], pack4(v));
        });
    } else {                // V region: direct path, transposed store
        const int tid = threadIdx.x, wave = tid >> 6, lane = tid & 63;
        const int wm = (wave & 1) * 64, wn = (wave >> 1) * 64;
        const int q = lane >> 4, ln = lane & 15;
#pragma unroll
        for (int tj = 0; tj < 4; ++tj) {
            const int gcol = col0 + wn + tj * 16 + ln;
            const float bv = bias[gcol];
#pragma unroll
            for (int ti = 0; ti < 4; ++ti) {
                const int grow = row0 + wm + ti * 16 + q * 4;
                const int b = grow >> 11, j = grow & (SEQ - 1);
                f32x4 vv;
                vv[0] = acc[ti][tj][0] + bv; vv[1] = acc[ti][tj][1] + bv;
                vv[2] = acc[ti][tj][2] + bv; vv[3] = acc[ti][tj][3] + bv;
                st16(&Vt[(size_t)b * CH * SEQ +
                         (size_t)(gcol - 2 * CH) * SEQ + j], pack4(vv));
            }
        }
    }
}

// ---------------------------------------------------------------------------
// QK^T (paired, A-IN-REGISTERS, B-dbuf counted-vmcnt — new this round).
// 512 thr / 8 waves, output 128x256. A (Q) fragments load straight
// global->VGPR each step (lane-contiguous 16B slices; Q is L2-hot via
// XCD=batch). LDS holds only B: double-buffered 2x32KB -> 2 blocks/CU.
// Per step: 8 A dwordx4 loads + 4 B llds16 (next step) + vmcnt(4) — the
// old full 48KB drain is gone; B(s+1) stays in flight across the barrier.
// vmcnt(4) correctness (issue-order accounting): outstanding entering step
// = B(s) 4; +8 A(s); +4 B(s+1) = 16 -> wait to 4 retires A(s)+B(s), leaves
// B(s+1). Last step: vmcnt(0). Grid 672 = 84 pair-units x 8 batches.
// ---------------------------------------------------------------------------
__global__ __launch_bounds__(512, 4) void qk2_gemm(
    const u16* __restrict__ Qb, const u16* __restrict__ Kb,
    u16* __restrict__ Sb, float* __restrict__ rowsum)
{
    __shared__ __align__(16) u16 SMEM[QK2_U16];      // B0 32KB | B1 32KB
    u16* const B0 = SMEM;                            // [256][64]
    u16* const B1 = SMEM + 16384;
    float* const eb = (float*)SMEM;                  // 32 x 260 fp32 = 33.3KB

    const int id = blockIdx.x;
    const int b = id & 7;
    int u = id >> 3, it, pr;                         // u = 0..83
    if (u < 32) { it = u >> 2; pr = u & 3; }
    else {
        int v = u - 32; it = 8; int len = 5;
        while (v >= len) { v -= len; ++it; len = 5 + ((it - 8) >> 1); }
        pr = v;
    }

    const int tid = threadIdx.x;
    const int w = tid >> 6, lane = tid & 63;
    const int wq = w & 3;
    const int wm = (wq & 1) * 64;
    const int wn = (w >> 2) * 128 + (wq >> 1) * 64;  // col within 256
    const int q = lane >> 4, ln = lane & 15;
    const int sr8 = lane >> 3, sc = (lane & 7) ^ sr8;

    const int row0 = it * 128, col0 = pr * 256;
    const u16* const Qg = Qb + (size_t)b * SEQ * CH;
    const u16* const Kg = Kb + (size_t)b * SEQ * CH;
    u16* const S = Sb + (size_t)b * SEQ * SEQ;

    // B staging: wave w owns K rows [col0+32w, +32) -> 4 llds16/step.
    const u16* gB = Kg + (size_t)(col0 + w * 32 + sr8) * CH + sc * 8;
    u16* const lB0 = B0 + w * 2048;
    u16* const lB1 = B1 + w * 2048;

    // A-frag base: this lane's Q row (m=ln within each 16-row tile), k
    // sub-chunk q*8. Per (h,t): + t*16 rows, + h*32 k. 16B-aligned.
    const u16* const gAf = Qg + (size_t)(row0 + wm + ln) * CH + q * 8;

    int boff[2][4];
#pragma unroll
    for (int h = 0; h < 2; ++h) {
        const int pos = (((h * 4 + q) ^ (ln & 7)) * 8);
#pragma unroll
        for (int t = 0; t < 4; ++t)
            boff[h][t] = (wn + t * 16 + ln) * 64 + pos;
    }

    f32x4 acc[4][4];
#pragma unroll
    for (int ti = 0; ti < 4; ++ti)
#pragma unroll
        for (int tj = 0; tj < 4; ++tj)
#pragma unroll
            for (int e = 0; e < 4; ++e) acc[ti][tj][e] = 0.f;

    // prologue: B(0) -> B0
#pragma unroll
    for (int i = 0; i < 4; ++i)
        llds16(gB + (size_t)(i * 8) * CH, lB0 + i * 512);

    for (int s = 0; s < 8; ++s) {
        // A fragments for step s: global -> VGPR (8 x dwordx4).
        bf16x8 af[2][4];
#pragma unroll
        for (int h = 0; h < 2; ++h)
#pragma unroll
            for (int t = 0; t < 4; ++t)
                af[h][t] = *(const bf16x8*)(gAf + (size_t)(t * 16) * CH
                                            + s * 64 + h * 32);
        if (s < 7) {
            u16* const nb = (s & 1) ? lB0 : lB1;
#pragma unroll
            for (int i = 0; i < 4; ++i)
                llds16(gB + (size_t)(i * 8) * CH + (s + 1) * 64, nb + i * 512);
            asm volatile("s_waitcnt vmcnt(4)" ::: "memory");
        } else {
            asm volatile("s_waitcnt vmcnt(0)" ::: "memory");
        }
        __builtin_amdgcn_s_barrier();    // B(s) visible to all waves
        const u16* const Bc = (s & 1) ? B1 : B0;
#pragma unroll
        for (int h = 0; h < 2; ++h) {
            bf16x8 bfv[4];
#pragma unroll
            for (int t = 0; t < 4; ++t)
                bfv[t] = *(const bf16x8*)&Bc[boff[h][t]];
#pragma unroll
            for (int ti = 0; ti < 4; ++ti)
#pragma unroll
                for (int tj = 0; tj < 4; ++tj)
                    acc[ti][tj] = __builtin_amdgcn_mfma_f32_16x16x32_bf16(
                        af[h][ti], bfv[tj], acc[ti][tj], 0, 0, 0);
        }
        __builtin_amdgcn_s_barrier();    // B(s) reads done before overwrite
        __builtin_amdgcn_sched_barrier(0);
    }

    // ---- epilogue: 4 passes of 32 rows x 256 cols (eb stride 260) ----
    const bool upper = (it < 8);
#pragma unroll
    for (int p = 0; p < 4; ++p) {
        __syncthreads();
        if ((wq & 1) == (p >> 1)) {
            const int tibase = (p & 1) * 2;
#pragma unroll
            for (int tj = 0; tj < 4; ++tj)
#pragma unroll
                for (int t2 = 0; t2 < 2; ++t2)
#pragma unroll
                    for (int r = 0; r < 4; ++r)
                        eb[(t2 * 16 + q * 4 + r) * 260 + wn + tj * 16 + ln] =
                            acc[tibase + t2][tj][r];
        }
        __syncthreads();
#pragma unroll
        for (int s2 = 0; s2 < 4; ++s2) {
            const int row = s2 * 8 + w;            // 0..31
            const int col = lane * 4;              // 0..252
            f32x4 v = *(const f32x4*)&eb[row * 260 + col];
            const int grow = row0 + p * 32 + row;
            const int gcol = col0 + col;
            f32x4 pv;
#pragma unroll
            for (int e = 0; e < 4; ++e) {
                const bool allowed = upper || (gcol + e <= grow);
                pv[e] = allowed ? fexp2(fminf(v[e], EXP2_CAP)) : 0.f;
            }
            st16(&S[(size_t)grow * SEQ + gcol], pack4(pv));
            float rs = pv[0] + pv[1] + pv[2] + pv[3];
            rs += __shfl_xor(rs, 1, 64);
            rs += __shfl_xor(rs, 2, 64);
            rs += __shfl_xor(rs, 4, 64);
            rs += __shfl_xor(rs, 8, 64);
            rs += __shfl_xor(rs, 16, 64);
            rs += __shfl_xor(rs, 32, 64);
            if (lane == 0)             // one row per wave per s2
                atomicAdd(&rowsum[b * SEQ + grow], rs);
        }
    }
}

// ---------------------------------------------------------------------------
// PV GEMM, full-K per block, normalized output. 1-D grid 512: b=id&7 ->
// XCD=batch (Vt 2MB L2-resident), heavy row-tiles first. Exactly one round.
// ---------------------------------------------------------------------------
__global__ __launch_bounds__(256) void pv_gemm(
    const u16* __restrict__ Sb, const u16* __restrict__ Vt,
    const float* __restrict__ rowsum, float* __restrict__ O)
{
    const int n = blockIdx.x;
    const int b = n & 7, m = n >> 3;        // m = 0..63
    const int it = 15 - (m >> 2), ct = m & 3;
    const int Kfull = ((it < 8) ? 8 : (it + 1)) * 128;
    __shared__ __align__(16) u16 SMEM[SMEM_U16];
    f32x4 acc[4][4];
    const u16* A  = Sb + (size_t)b * SEQ * SEQ;
    const u16* Bt = Vt + (size_t)b * CH * SEQ;
    const int row0 = it * 128, col0 = ct * 128;
    mm_core(A, SEQ, Bt, SEQ, row0, col0, Kfull, SMEM, acc);

    epi_emit(acc, (float*)SMEM, [&](int row, int col, f32x4 v) {
        const int grow = row0 + row;
        const float rden = 1.0f / rowsum[b * SEQ + grow];
        v[0] *= rden; v[1] *= rden; v[2] *= rden; v[3] *= rden;
        st16f(&O[(size_t)(b * SEQ + grow) * CH + col0 + col], v);
    });
}

// ---------------------------------------------------------------------------
// fc1: bf16 in/out, exact GELU epilogue. Row-panel XCD swizzle.
// ---------------------------------------------------------------------------
__global__ __launch_bounds__(256) void fc1_gemm(
    const u16* __restrict__ A, const u16* __restrict__ Bt,
    const float* __restrict__ bias, u16* __restrict__ H)
{
    __shared__ __align__(16) u16 SMEM[SMEM_U16];
    f32x4 acc[4][4];
    int rt, ct; xcd_rc(rt, ct);
    const int row0 = rt * 128, col0 = ct * 128;
    mm_core(A, CH, Bt, CH, row0, col0, CH, SMEM, acc);
    epi_emit(acc, (float*)SMEM, [&](int row, int col, f32x4 v) {
        const float4 bb = *(const float4*)&bias[col0 + col];
        v[0] += bb.x; v[1] += bb.y; v[2] += bb.z; v[3] += bb.w;
#pragma unroll
        for (int e = 0; e < 4; ++e)
            v[e] = 0.5f * v[e] * (1.f + erff(v[e] * 0.70710678118654752f));
        st16(&H[(size_t)(row0 + row) * (2 * CH) + col0 + col], pack4(v));
    });
}

// ---------------------------------------------------------------------------
// fc2: bf16 in, +bias + fp32 residual (normalized O). Writes bf16 Xb always;
// fp32 X only on the final layer. Row-panel XCD swizzle.
// ---------------------------------------------------------------------------
template <bool WRITE_X>
__global__ __launch_bounds__(256) void fc2_gemm(
    const u16* __restrict__ A, const u16* __restrict__ Bt,
    const float* __restrict__ bias, float* __restrict__ X,
    u16* __restrict__ Xb)
{
    __shared__ __align__(16) u16 SMEM[SMEM_U16];
    f32x4 acc[4][4];
    int rt, ct; xcd_rc(rt, ct);
    const int row0 = rt * 128, col0 = ct * 128;
    mm_core(A, 2 * CH, Bt, 2 * CH, row0, col0, 2 * CH, SMEM, acc);
    epi_emit(acc, (float*)SMEM, [&](int row, int col, f32x4 v) {
        const size_t idx = (size_t)(row0 + row) * CH + col0 + col;
        const float4 bb = *(const float4*)&bias[col0 + col];
        const f32x4 xv = *(const f32x4*)&X[idx];
        v[0] += bb.x + xv[0]; v[1] += bb.y + xv[1];
        v[2] += bb.z + xv[2]; v[3] += bb.w + xv[3];
        if (WRITE_X) st16f(&X[idx], v);
        st16(&Xb[idx], pack4(v));
    });
}

// ---------------------------------------------------------------------------
// LayerNorm, WAVE-PER-ROW: one row = 64 lanes x 8 f32; reductions are 12
// shfl_xor, no __syncthreads / LDS. 4 rows/block, grid 4096, XCD-aligned.
// ---------------------------------------------------------------------------
__global__ __launch_bounds__(256) void ln_kernel(
    const float* __restrict__ x, const float* __restrict__ g,
    const float* __restrict__ bta, u16* __restrict__ y)
{
    const int tid = threadIdx.x, wave = tid >> 6, lane = tid & 63;
    const int row = (blockIdx.x & 7) * SEQ + (blockIdx.x >> 3) * 4 + wave;
    const size_t base = (size_t)row * CH + lane * 8;
    const float4 a = *(const float4*)&x[base];
    const float4 b = *(const float4*)&x[base + 4];
    float s = a.x + a.y + a.z + a.w + b.x + b.y + b.z + b.w;
#pragma unroll
    for (int off = 1; off < 64; off <<= 1) s += __shfl_xor(s, off, 64);
    const float mu = s * (1.f / CH);
    float d[8] = { a.x - mu, a.y - mu, a.z - mu, a.w - mu,
                   b.x - mu, b.y - mu, b.z - mu, b.w - mu };
    float ss = 0.f;
#pragma unroll
    for (int e = 0; e < 8; ++e) ss += d[e] * d[e];
#pragma unroll
    for (int off = 1; off < 64; off <<= 1) ss += __shfl_xor(ss, off, 64);
    const float w = 1.f / sqrtf(ss * (1.f / CH) + 1e-5f);
    const int c = lane * 8;
    const float4 g0 = *(const float4*)&g[c],   g1 = *(const float4*)&g[c + 4];
    const float4 t0 = *(const float4*)&bta[c], t1 = *(const float4*)&bta[c + 4];
    uint4 o;
    o.x = pk2(d[0] * w * g0.x + t0.x, d[1] * w * g0.y + t0.y);
    o.y = pk2(d[2] * w * g0.z + t0.z, d[3] * w * g0.w + t0.w);
    o.z = pk2(d[4] * w * g1.x + t1.x, d[5] * w * g1.y + t1.y);
    o.w = pk2(d[6] * w * g1.z + t1.z, d[7] * w * g1.w + t1.w);
    *(uint4*)&y[base] = o;
}

// ---------------------------------------------------------------------------
// fp32 -> bf16 elementwise (4/thread).
// ---------------------------------------------------------------------------
__global__ __launch_bounds__(256) void f2bf_kernel(
    const float* __restrict__ in, u16* __restrict__ out)
{
    const int i = blockIdx.x * 256 + threadIdx.x;
    float4 vv = ((const float4*)in)[i];
    f32x4 v; v[0] = vv.x; v[1] = vv.y; v[2] = vv.z; v[3] = vv.w;
    u16x4 o = pack4(v);
    *(u16x4*)&out[(size_t)i * 4] = o;
}

// ---------------------------------------------------------------------------
// Weight transpose-convert: in fp32 [L][K][N] -> out bf16 [L][N][K].
// ---------------------------------------------------------------------------
__global__ __launch_bounds__(256) void wtrans_kernel(
    const float* __restrict__ in, u16* __restrict__ out, int K, int N)
{
    __shared__ float tile[32][33];
    const int l = blockIdx.z;
    in  += (size_t)l * K * N;
    out += (size_t)l * K * N;
    const int n0 = blockIdx.x * 32, k0 = blockIdx.y * 32;
    const int r = threadIdx.x >> 3, c4 = (threadIdx.x & 7) * 4;
    float4 v = *(const float4*)&in[(size_t)(k0 + r) * N + n0 + c4];
    tile[r][c4 + 0] = v.x; tile[r][c4 + 1] = v.y;
    tile[r][c4 + 2] = v.z; tile[r][c4 + 3] = v.w;
    __syncthreads();
    f32x4 t;
    t[0] = tile[c4 + 0][r]; t[1] = tile[c4 + 1][r];
    t[2] = tile[c4 + 2][r]; t[3] = tile[c4 + 3][r];
    st16(&out[(size_t)(n0 + r) * K + k0 + c4], pack4(t));
}

// ---------------------------------------------------------------------------
extern "C" void kernel_launch(void* const* d_in, const int* in_sizes, int n_in,
                              void* d_out, int out_size, void* d_ws, size_t ws_size,
                              hipStream_t stream)
{
    const float* x_in  = (const float*)d_in[0];
    const float* qkv_w = (const float*)d_in[1];
    const float* qkv_b = (const float*)d_in[2];
    const float* ln_g  = (const float*)d_in[3];
    const float* ln_b  = (const float*)d_in[4];
    const float* fc1_w = (const float*)d_in[5];
    const float* fc1_b = (const float*)d_in[6];
    const float* fc2_w = (const float*)d_in[7];
    const float* fc2_b = (const float*)d_in[8];

    float* xbuf = (float*)d_out;   // fp32 working x (B,N,C) — also final out

    // Workspace carve (bytes). Total ≈ 152.7 MB.
    char* p = (char*)d_ws;
    u16* qkv_wt = (u16*)p; p += (size_t)NLAYERS * 1536 * 512 * 2;
    u16* fc1_wt = (u16*)p; p += (size_t)NLAYERS * 1024 * 512 * 2;
    u16* fc2_wt = (u16*)p; p += (size_t)NLAYERS * 512 * 1024 * 2;
    u16* xb = (u16*)p; p += (size_t)ROWS_TOTAL * CH * 2;
    u16* Qb = (u16*)p; p += (size_t)ROWS_TOTAL * CH * 2;
    u16* Kb = (u16*)p; p += (size_t)ROWS_TOTAL * CH * 2;
    u16* Vt = (u16*)p; p += (size_t)ROWS_TOTAL * CH * 2;
    float* rowsum = (float*)p; p += (size_t)ROWS_TOTAL * 4;
    u16* Sb = (u16*)p;                       // attention phase
    u16* yb = Sb;                            // alias: LN out (MLP phase)
    u16* hb = Sb + (size_t)ROWS_TOTAL * CH;  // alias: GELU out (MLP phase)

    const dim3 blk(256);
    const dim3 blk2(512);

    f2bf_kernel<<<dim3(ROWS_TOTAL * CH / 1024), blk, 0, stream>>>(x_in, xb);
    wtrans_kernel<<<dim3(1536 / 32, 512 / 32, NLAYERS), blk, 0, stream>>>(
        qkv_w, qkv_wt, 512, 1536);
    wtrans_kernel<<<dim3(1024 / 32, 512 / 32, NLAYERS), blk, 0, stream>>>(
        fc1_w, fc1_wt, 512, 1024);
    wtrans_kernel<<<dim3(512 / 32, 1024 / 32, NLAYERS), blk, 0, stream>>>(
        fc2_w, fc2_wt, 1024, 512);

    for (int l = 0; l < NLAYERS; ++l) {
        qkv_gemm<<<dim3(128 * 12), blk, 0, stream>>>(
            xb, qkv_wt + (size_t)l * 1536 * 512, qkv_b + (size_t)l * 1536,
            Qb, Kb, Vt, rowsum);
        qk2_gemm<<<dim3(672), blk2, 0, stream>>>(Qb, Kb, Sb, rowsum);
        pv_gemm<<<dim3(512), blk, 0, stream>>>(Sb, Vt, rowsum, xbuf);
        ln_kernel<<<dim3(ROWS_TOTAL / 4), blk, 0, stream>>>(
            xbuf, ln_g + (size_t)l * CH, ln_b + (size_t)l * CH, yb);
        fc1_gemm<<<dim3(128 * 8), blk, 0, stream>>>(
            yb, fc1_wt + (size_t)l * 1024 * 512, fc1_b + (size_t)l * 1024, hb);
        if (l < NLAYERS - 1)
            fc2_gemm<false><<<dim3(128 * 4), blk, 0, stream>>>(
                hb, fc2_wt + (size_t)l * 512 * 1024, fc2_b + (size_t)l * 512,
                xbuf, xb);
        else
            fc2_gemm<true><<<dim3(128 * 4), blk, 0, stream>>>(
                hb, fc2_wt + (size_t)l * 512 * 1024, fc2_b + (size_t)l * 512,
                xbuf, xb);
    }
}

// Round 11
// 939.528 us; speedup vs baseline: 1.1885x; 1.1885x over previous
//
#include <hip/hip_runtime.h>
#include <math.h>

typedef unsigned short u16;
typedef __attribute__((ext_vector_type(8))) short bf16x8;
typedef __attribute__((ext_vector_type(4))) float f32x4;
typedef __attribute__((ext_vector_type(4))) unsigned short u16x4;

#define NLAYERS 5
#define BATCH 8
#define SEQ 2048
#define CH 512
#define ROWS_TOTAL (BATCH * SEQ)   // 16384
#define HALF (SEQ / 2)             // 1024
// Q prescale folds softmax scale AND log2(e): qk's epilogue is then a bare
// v_exp_f32 (exp2). 512^-0.5 * 1.4426950408889634 :
#define QSCALE_EXP2 0.06375871529f
// exp cap in exp2 domain (= old 60.0 in e-domain).
#define EXP2_CAP 86.56f

// 128-sq dbuf core (qkv/pv/fc1/fc2): {As0,Bs0,As1,Bs1} x 16 KB = 64 KB
// -> 2 blocks/CU.
#define SMEM_U16 32768
// qk2 v3: A single 16KB + B double 2x32KB = 80KB -> 2 blocks/CU.
// (Round-8 lesson: A-in-regs is uncoalesced + loses pair-sharing — A stays
// in LDS. Round-5 lesson: the full 48KB drain per step is the stall; B now
// streams through a counted-vmcnt dbuf, only A (16KB) rides the drain.)
#define QK2_U16 40960

__device__ __forceinline__ u16 f2bf(float f) {
    unsigned u = __float_as_uint(f);
    u += 0x7fffu + ((u >> 16) & 1u);   // RNE (scalar fallback)
    return (u16)(u >> 16);
}

__device__ __forceinline__ unsigned pk2(float a, float b) {
    unsigned r;
    asm("v_cvt_pk_bf16_f32 %0, %1, %2" : "=v"(r) : "v"(a), "v"(b));
    return r;
}

__device__ __forceinline__ u16x4 pack4(f32x4 v) {
    union { unsigned u[2]; u16x4 o; } r;
    r.u[0] = pk2(v[0], v[1]);
    r.u[1] = pk2(v[2], v[3]);
    return r.o;
}

__device__ __forceinline__ void st16(u16* p, u16x4 v) { *(u16x4*)p = v; }
__device__ __forceinline__ void st16f(float* p, f32x4 v) { *(f32x4*)p = v; }

__device__ __forceinline__ float fexp2(float x) {
    float r;
    asm("v_exp_f32 %0, %1" : "=v"(r) : "v"(x));
    return r;
}

// 16-byte async global->LDS DMA. LDS dest = wave-uniform base + lane*16.
__device__ __forceinline__ void llds16(const u16* g, u16* l) {
    __builtin_amdgcn_global_load_lds(
        (const __attribute__((address_space(1))) unsigned int*)g,
        (__attribute__((address_space(3))) unsigned int*)l, 16, 0, 0);
}

// XCD-aware decode for M=16384 row-panel GEMMs (qkv/fc1/fc2): XCD k
// (bid&7) owns row-tiles [16k,16k+16) for all col-tiles -> per-XCD L2
// working set = A-panel 2.1 MB + W <= 1.6 MB < 4 MB.
__device__ __forceinline__ void xcd_rc(int& rt, int& ct) {
    const int n = blockIdx.x;
    const int m = n >> 3;
    rt = (n & 7) * 16 + (m & 15);
    ct = m >> 4;
}

// ---------------------------------------------------------------------------
// mm_compute: one BK=64 step of a 64x64 wave-tile (32 MFMAs). Frag layout
// (verified): A [m=lane&15][k=quad*8+j]; C/D col=lane&15, row=quad*4+reg.
// aoff/boff carry the chunk-XOR (0 bank conflicts measured).
// ---------------------------------------------------------------------------
__device__ __forceinline__ void mm_compute(const u16* As, const u16* Bs,
                                           const int aoff[2][4],
                                           const int boff[2][4],
                                           f32x4 acc[4][4])
{
#pragma unroll
    for (int h = 0; h < 2; ++h) {
        bf16x8 af[4], bfv[4];
#pragma unroll
        for (int t = 0; t < 4; ++t) af[t]  = *(const bf16x8*)&As[aoff[h][t]];
#pragma unroll
        for (int t = 0; t < 4; ++t) bfv[t] = *(const bf16x8*)&Bs[boff[h][t]];
#pragma unroll
        for (int ti = 0; ti < 4; ++ti)
#pragma unroll
            for (int tj = 0; tj < 4; ++tj)
                acc[ti][tj] = __builtin_amdgcn_mfma_f32_16x16x32_bf16(
                    af[ti], bfv[tj], acc[ti][tj], 0, 0, 0);
    }
}

// ---------------------------------------------------------------------------
// 128-sq dbuf core: 128x128 C-tile, 256 threads (4 waves, 2x2 of 64x64),
// BK=64. 2-deep double buffer, raw s_barrier + counted s_waitcnt vmcnt(8):
// next tile's 8 global_load_lds stay in flight across the barrier.
// ---------------------------------------------------------------------------
__device__ __forceinline__ void mm_issue(const u16* gA, const u16* gB,
                                         u16* lA, u16* lB, int lda, int ldb)
{
#pragma unroll
    for (int i = 0; i < 4; ++i)
        llds16(gA + (size_t)i * 32 * lda, lA + i * 2048);
#pragma unroll
    for (int i = 0; i < 4; ++i)
        llds16(gB + (size_t)i * 32 * ldb, lB + i * 2048);
}

__device__ __forceinline__ void mm_core(
    const u16* __restrict__ A, int lda,
    const u16* __restrict__ Bt, int ldb,
    int row0, int col0, int K,
    u16* SM, f32x4 acc[4][4])
{
    const int tid  = threadIdx.x;
    const int wave = tid >> 6, lane = tid & 63;
    const int wm = (wave & 1) * 64, wn = (wave >> 1) * 64;
    const int q  = lane >> 4,  ln = lane & 15;

    const int sr8 = lane >> 3;
    const int sc  = (lane & 7) ^ sr8;
    const u16* gA = A  + (size_t)(row0 + wave * 8 + sr8) * lda + sc * 8;
    const u16* gB = Bt + (size_t)(col0 + wave * 8 + sr8) * ldb + sc * 8;

    u16* const A0 = SM;
    u16* const B0 = SM + 8192;
    u16* const A1 = SM + 16384;
    u16* const B1 = SM + 24576;
    u16* const w0a = A0 + wave * 512;
    u16* const w0b = B0 + wave * 512;
    u16* const w1a = A1 + wave * 512;
    u16* const w1b = B1 + wave * 512;

    int aoff[2][4], boff[2][4];
#pragma unroll
    for (int h = 0; h < 2; ++h) {
        const int pos = (((h * 4 + q) ^ (ln & 7)) * 8);
#pragma unroll
        for (int t = 0; t < 4; ++t) {
            aoff[h][t] = (wm + t * 16 + ln) * 64 + pos;
            boff[h][t] = (wn + t * 16 + ln) * 64 + pos;
        }
    }

#pragma unroll
    for (int ti = 0; ti < 4; ++ti)
#pragma unroll
        for (int tj = 0; tj < 4; ++tj)
#pragma unroll
            for (int e = 0; e < 4; ++e) acc[ti][tj][e] = 0.f;

    mm_issue(gA, gB, w0a, w0b, lda, ldb);
    gA += 64; gB += 64;

    for (int k0 = 0; k0 < K; k0 += 128) {
        if (k0 + 64 < K) {
            mm_issue(gA, gB, w1a, w1b, lda, ldb);
            gA += 64; gB += 64;
            asm volatile("s_waitcnt vmcnt(8)" ::: "memory");
        } else {
            asm volatile("s_waitcnt vmcnt(0)" ::: "memory");
        }
        __builtin_amdgcn_s_barrier();
        mm_compute(A0, B0, aoff, boff, acc);
        __builtin_amdgcn_s_barrier();
        __builtin_amdgcn_sched_barrier(0);
        if (k0 + 128 < K) {
            mm_issue(gA, gB, w0a, w0b, lda, ldb);
            gA += 64; gB += 64;
            asm volatile("s_waitcnt vmcnt(8)" ::: "memory");
        } else {
            asm volatile("s_waitcnt vmcnt(0)" ::: "memory");
        }
        __builtin_amdgcn_s_barrier();
        mm_compute(A1, B1, aoff, boff, acc);
        __builtin_amdgcn_s_barrier();
        __builtin_amdgcn_sched_barrier(0);
    }
}

// Epilogue transpose (128-sq core), 4 passes of 32 rows, eb 32x132 fp32
// (132 == 4 mod 32, conflict-free).
template <typename F>
__device__ __forceinline__ void epi_emit(f32x4 acc[4][4], float* eb, F emit)
{
    const int tid = threadIdx.x, wave = tid >> 6, lane = tid & 63;
    const int wn = (wave >> 1) * 64;
    const int q = lane >> 4, ln = lane & 15;
#pragma unroll
    for (int p = 0; p < 4; ++p) {
        __syncthreads();
        if ((wave & 1) == (p >> 1)) {
            const int tibase = (p & 1) * 2;
#pragma unroll
            for (int tj = 0; tj < 4; ++tj)
#pragma unroll
                for (int t2 = 0; t2 < 2; ++t2)
#pragma unroll
                    for (int r = 0; r < 4; ++r)
                        eb[(t2 * 16 + q * 4 + r) * 132 + wn + tj * 16 + ln] =
                            acc[tibase + t2][tj][r];
        }
        __syncthreads();
#pragma unroll
        for (int s = 0; s < 4; ++s) {
            const int row = s * 8 + (tid >> 5);        // 0..31
            const int col = (tid & 31) * 4;
            f32x4 v = *(const f32x4*)&eb[row * 132 + col];
            emit(p * 32 + row, col, v);
        }
    }
}

// ---------------------------------------------------------------------------
// QKV GEMM: A=xb[16384][512], Bt=qkv_wt[1536][512]. 1-D grid (128*12),
// row-panel XCD swizzle. Q (pre-scaled by QSCALE_EXP2) and K use the
// vectorized epi; V region (ct>=8) keeps the direct acc path (transposed
// store Vt[b][c][j]). ct==0 blocks also zero rowsum.
// ---------------------------------------------------------------------------
__global__ __launch_bounds__(256) void qkv_gemm(
    const u16* __restrict__ A, const u16* __restrict__ Bt,
    const float* __restrict__ bias,
    u16* __restrict__ Qb, u16* __restrict__ Kb, u16* __restrict__ Vt,
    float* __restrict__ rowsum)
{
    __shared__ __align__(16) u16 SMEM[SMEM_U16];
    f32x4 acc[4][4];
    int rt, ct; xcd_rc(rt, ct);
    const int row0 = rt * 128, col0 = ct * 128;
    if (ct == 0 && threadIdx.x < 128)
        rowsum[row0 + threadIdx.x] = 0.f;
    mm_core(A, CH, Bt, CH, row0, col0, CH, SMEM, acc);

    if (ct < 8) {   // Q or K region (block-uniform)
        u16* dst = (ct < 4) ? Qb : Kb;
        const int cbase = (ct < 4) ? col0 : col0 - CH;
        const float sc = (ct < 4) ? QSCALE_EXP2 : 1.0f;
        epi_emit(acc, (float*)SMEM, [&](int row, int col, f32x4 v) {
            const float4 bb = *(const float4*)&bias[col0 + col];
            v[0] = (v[0] + bb.x) * sc; v[1] = (v[1] + bb.y) * sc;
            v[2] = (v[2] + bb.z) * sc; v[3] = (v[3] + bb.w) * sc;
            st16(&dst[(size_t)(row0 + row) * CH + cbase + col], pack4(v));
        });
    } else {                // V region: direct path, transposed store
        const int tid = threadIdx.x, wave = tid >> 6, lane = tid & 63;
        const int wm = (wave & 1) * 64, wn = (wave >> 1) * 64;
        const int q = lane >> 4, ln = lane & 15;
#pragma unroll
        for (int tj = 0; tj < 4; ++tj) {
            const int gcol = col0 + wn + tj * 16 + ln;
            const float bv = bias[gcol];
#pragma unroll
            for (int ti = 0; ti < 4; ++ti) {
                const int grow = row0 + wm + ti * 16 + q * 4;
                const int b = grow >> 11, j = grow & (SEQ - 1);
                f32x4 vv;
                vv[0] = acc[ti][tj][0] + bv; vv[1] = acc[ti][tj][1] + bv;
                vv[2] = acc[ti][tj][2] + bv; vv[3] = acc[ti][tj][3] + bv;
                st16(&Vt[(size_t)b * CH * SEQ +
                         (size_t)(gcol - 2 * CH) * SEQ + j], pack4(vv));
            }
        }
    }
}

// ---------------------------------------------------------------------------
// QK^T v3 (paired; A in LDS single-buffer, B double-buffered with counted
// vmcnt). 512 thr / 8 waves, output 128x256; A (Q, 16KB) shared by both
// pair halves; B (K) streams through 2x32KB with vmcnt(4) so B(s+1) stays
// in flight across both barriers. Issue-order invariant entering step s:
// {B(s)[4 oldest], A(s)[2], B(s+1)[4 newest]} -> vmcnt(4) retires exactly
// B(s)+A(s). A(s+1)/B(s+2) issue right after the compute-end barrier (their
// buffers' reads just drained). LDS 80KB -> 2 blocks/CU. Grid 672.
// ---------------------------------------------------------------------------
__global__ __launch_bounds__(512, 4) void qk2_gemm(
    const u16* __restrict__ Qb, const u16* __restrict__ Kb,
    u16* __restrict__ Sb, float* __restrict__ rowsum)
{
    __shared__ __align__(16) u16 SMEM[QK2_U16];   // A 16KB | B0 32KB | B1 32KB
    u16* const As = SMEM;                         // [128][64]
    u16* const B0 = SMEM + 8192;                  // [256][64]
    u16* const B1 = SMEM + 24576;
    float* const eb = (float*)SMEM;               // 32 x 260 fp32 = 33.3KB

    const int id = blockIdx.x;
    const int b = id & 7;
    int u = id >> 3, it, pr;                      // u = 0..83
    if (u < 32) { it = u >> 2; pr = u & 3; }
    else {
        int v = u - 32; it = 8; int len = 5;
        while (v >= len) { v -= len; ++it; len = 5 + ((it - 8) >> 1); }
        pr = v;
    }

    const int tid = threadIdx.x;
    const int w = tid >> 6, lane = tid & 63;
    const int wq = w & 3;
    const int wm = (wq & 1) * 64;
    const int wn = (w >> 2) * 128 + (wq >> 1) * 64;   // col within 256
    const int q = lane >> 4, ln = lane & 15;
    const int sr8 = lane >> 3, sc = (lane & 7) ^ sr8;

    const int row0 = it * 128, col0 = pr * 256;
    const u16* const Qg = Qb + (size_t)b * SEQ * CH;
    const u16* const Kg = Kb + (size_t)b * SEQ * CH;
    u16* const S = Sb + (size_t)b * SEQ * SEQ;

    // A staging: wave w owns Q rows [row0+16w, +16) -> 2 llds16/step.
    const u16* gA = Qg + (size_t)(row0 + w * 16 + sr8) * CH + sc * 8;
    u16* const lA = As + w * 1024;
    // B staging: wave w owns K rows [col0+32w, +32) -> 4 llds16/buffer.
    const u16* gB = Kg + (size_t)(col0 + w * 32 + sr8) * CH + sc * 8;
    u16* const lB0 = B0 + w * 2048;
    u16* const lB1 = B1 + w * 2048;

    int aoff[2][4], boff[2][4];
#pragma unroll
    for (int h = 0; h < 2; ++h) {
        const int pos = (((h * 4 + q) ^ (ln & 7)) * 8);
#pragma unroll
        for (int t = 0; t < 4; ++t) {
            aoff[h][t] = (wm + t * 16 + ln) * 64 + pos;
            boff[h][t] = (wn + t * 16 + ln) * 64 + pos;
        }
    }

    f32x4 acc[4][4];
#pragma unroll
    for (int ti = 0; ti < 4; ++ti)
#pragma unroll
        for (int tj = 0; tj < 4; ++tj)
#pragma unroll
            for (int e = 0; e < 4; ++e) acc[ti][tj][e] = 0.f;

    // Prologue (issue order defines vmcnt accounting): B(0), A(0), B(1).
#pragma unroll
    for (int i = 0; i < 4; ++i)
        llds16(gB + (size_t)(i * 8) * CH, lB0 + i * 512);
    llds16(gA,                  lA);
    llds16(gA + (size_t)8 * CH, lA + 512);
#pragma unroll
    for (int i = 0; i < 4; ++i)
        llds16(gB + (size_t)(i * 8) * CH + 64, lB1 + i * 512);

    for (int s = 0; s < 8; ++s) {
        if (s < 7)
            asm volatile("s_waitcnt vmcnt(4)" ::: "memory"); // keep B(s+1)
        else
            asm volatile("s_waitcnt vmcnt(0)" ::: "memory");
        __builtin_amdgcn_s_barrier();          // A(s), B(s) visible
        mm_compute(As, (s & 1) ? B1 : B0, aoff, boff, acc);
        __builtin_amdgcn_s_barrier();          // reads of As, B(s&1) done
        __builtin_amdgcn_sched_barrier(0);
        if (s < 7) {
            llds16(gA + (s + 1) * 64,                    lA);
            llds16(gA + (s + 1) * 64 + (size_t)8 * CH,   lA + 512);
            if (s < 6) {
                u16* const nb = (s & 1) ? lB1 : lB0;     // holds B(s), freed
#pragma unroll
                for (int i = 0; i < 4; ++i)
                    llds16(gB + (size_t)(i * 8) * CH + (s + 2) * 64,
                           nb + i * 512);
            }
        }
    }

    // ---- epilogue: 4 passes of 32 rows x 256 cols (eb stride 260) ----
    const bool upper = (it < 8);
#pragma unroll
    for (int p = 0; p < 4; ++p) {
        __syncthreads();
        if ((wq & 1) == (p >> 1)) {
            const int tibase = (p & 1) * 2;
#pragma unroll
            for (int tj = 0; tj < 4; ++tj)
#pragma unroll
                for (int t2 = 0; t2 < 2; ++t2)
#pragma unroll
                    for (int r = 0; r < 4; ++r)
                        eb[(t2 * 16 + q * 4 + r) * 260 + wn + tj * 16 + ln] =
                            acc[tibase + t2][tj][r];
        }
        __syncthreads();
#pragma unroll
        for (int s2 = 0; s2 < 4; ++s2) {
            const int row = s2 * 8 + w;            // 0..31
            const int col = lane * 4;              // 0..252
            f32x4 v = *(const f32x4*)&eb[row * 260 + col];
            const int grow = row0 + p * 32 + row;
            const int gcol = col0 + col;
            f32x4 pv;
#pragma unroll
            for (int e = 0; e < 4; ++e) {
                const bool allowed = upper || (gcol + e <= grow);
                pv[e] = allowed ? fexp2(fminf(v[e], EXP2_CAP)) : 0.f;
            }
            st16(&S[(size_t)grow * SEQ + gcol], pack4(pv));
            float rs = pv[0] + pv[1] + pv[2] + pv[3];
            rs += __shfl_xor(rs, 1, 64);
            rs += __shfl_xor(rs, 2, 64);
            rs += __shfl_xor(rs, 4, 64);
            rs += __shfl_xor(rs, 8, 64);
            rs += __shfl_xor(rs, 16, 64);
            rs += __shfl_xor(rs, 32, 64);
            if (lane == 0)             // one row per wave per s2
                atomicAdd(&rowsum[b * SEQ + grow], rs);
        }
    }
}

// ---------------------------------------------------------------------------
// PV GEMM, full-K per block, normalized output. 1-D grid 512: b=id&7 ->
// XCD=batch (Vt 2MB L2-resident), heavy row-tiles first. Exactly one round.
// ---------------------------------------------------------------------------
__global__ __launch_bounds__(256) void pv_gemm(
    const u16* __restrict__ Sb, const u16* __restrict__ Vt,
    const float* __restrict__ rowsum, float* __restrict__ O)
{
    const int n = blockIdx.x;
    const int b = n & 7, m = n >> 3;        // m = 0..63
    const int it = 15 - (m >> 2), ct = m & 3;
    const int Kfull = ((it < 8) ? 8 : (it + 1)) * 128;
    __shared__ __align__(16) u16 SMEM[SMEM_U16];
    f32x4 acc[4][4];
    const u16* A  = Sb + (size_t)b * SEQ * SEQ;
    const u16* Bt = Vt + (size_t)b * CH * SEQ;
    const int row0 = it * 128, col0 = ct * 128;
    mm_core(A, SEQ, Bt, SEQ, row0, col0, Kfull, SMEM, acc);

    epi_emit(acc, (float*)SMEM, [&](int row, int col, f32x4 v) {
        const int grow = row0 + row;
        const float rden = 1.0f / rowsum[b * SEQ + grow];
        v[0] *= rden; v[1] *= rden; v[2] *= rden; v[3] *= rden;
        st16f(&O[(size_t)(b * SEQ + grow) * CH + col0 + col], v);
    });
}

// ---------------------------------------------------------------------------
// fc1: bf16 in/out, exact GELU epilogue. Row-panel XCD swizzle.
// ---------------------------------------------------------------------------
__global__ __launch_bounds__(256) void fc1_gemm(
    const u16* __restrict__ A, const u16* __restrict__ Bt,
    const float* __restrict__ bias, u16* __restrict__ H)
{
    __shared__ __align__(16) u16 SMEM[SMEM_U16];
    f32x4 acc[4][4];
    int rt, ct; xcd_rc(rt, ct);
    const int row0 = rt * 128, col0 = ct * 128;
    mm_core(A, CH, Bt, CH, row0, col0, CH, SMEM, acc);
    epi_emit(acc, (float*)SMEM, [&](int row, int col, f32x4 v) {
        const float4 bb = *(const float4*)&bias[col0 + col];
        v[0] += bb.x; v[1] += bb.y; v[2] += bb.z; v[3] += bb.w;
#pragma unroll
        for (int e = 0; e < 4; ++e)
            v[e] = 0.5f * v[e] * (1.f + erff(v[e] * 0.70710678118654752f));
        st16(&H[(size_t)(row0 + row) * (2 * CH) + col0 + col], pack4(v));
    });
}

// ---------------------------------------------------------------------------
// fc2: bf16 in, +bias + fp32 residual (normalized O). Writes bf16 Xb always;
// fp32 X only on the final layer. Row-panel XCD swizzle.
// ---------------------------------------------------------------------------
template <bool WRITE_X>
__global__ __launch_bounds__(256) void fc2_gemm(
    const u16* __restrict__ A, const u16* __restrict__ Bt,
    const float* __restrict__ bias, float* __restrict__ X,
    u16* __restrict__ Xb)
{
    __shared__ __align__(16) u16 SMEM[SMEM_U16];
    f32x4 acc[4][4];
    int rt, ct; xcd_rc(rt, ct);
    const int row0 = rt * 128, col0 = ct * 128;
    mm_core(A, 2 * CH, Bt, 2 * CH, row0, col0, 2 * CH, SMEM, acc);
    epi_emit(acc, (float*)SMEM, [&](int row, int col, f32x4 v) {
        const size_t idx = (size_t)(row0 + row) * CH + col0 + col;
        const float4 bb = *(const float4*)&bias[col0 + col];
        const f32x4 xv = *(const f32x4*)&X[idx];
        v[0] += bb.x + xv[0]; v[1] += bb.y + xv[1];
        v[2] += bb.z + xv[2]; v[3] += bb.w + xv[3];
        if (WRITE_X) st16f(&X[idx], v);
        st16(&Xb[idx], pack4(v));
    });
}

// ---------------------------------------------------------------------------
// LayerNorm, WAVE-PER-ROW: one row = 64 lanes x 8 f32; reductions are 12
// shfl_xor, no __syncthreads / LDS. 4 rows/block, grid 4096, XCD-aligned.
// ---------------------------------------------------------------------------
__global__ __launch_bounds__(256) void ln_kernel(
    const float* __restrict__ x, const float* __restrict__ g,
    const float* __restrict__ bta, u16* __restrict__ y)
{
    const int tid = threadIdx.x, wave = tid >> 6, lane = tid & 63;
    const int row = (blockIdx.x & 7) * SEQ + (blockIdx.x >> 3) * 4 + wave;
    const size_t base = (size_t)row * CH + lane * 8;
    const float4 a = *(const float4*)&x[base];
    const float4 b = *(const float4*)&x[base + 4];
    float s = a.x + a.y + a.z + a.w + b.x + b.y + b.z + b.w;
#pragma unroll
    for (int off = 1; off < 64; off <<= 1) s += __shfl_xor(s, off, 64);
    const float mu = s * (1.f / CH);
    float d[8] = { a.x - mu, a.y - mu, a.z - mu, a.w - mu,
                   b.x - mu, b.y - mu, b.z - mu, b.w - mu };
    float ss = 0.f;
#pragma unroll
    for (int e = 0; e < 8; ++e) ss += d[e] * d[e];
#pragma unroll
    for (int off = 1; off < 64; off <<= 1) ss += __shfl_xor(ss, off, 64);
    const float w = 1.f / sqrtf(ss * (1.f / CH) + 1e-5f);
    const int c = lane * 8;
    const float4 g0 = *(const float4*)&g[c],   g1 = *(const float4*)&g[c + 4];
    const float4 t0 = *(const float4*)&bta[c], t1 = *(const float4*)&bta[c + 4];
    uint4 o;
    o.x = pk2(d[0] * w * g0.x + t0.x, d[1] * w * g0.y + t0.y);
    o.y = pk2(d[2] * w * g0.z + t0.z, d[3] * w * g0.w + t0.w);
    o.z = pk2(d[4] * w * g1.x + t1.x, d[5] * w * g1.y + t1.y);
    o.w = pk2(d[6] * w * g1.z + t1.z, d[7] * w * g1.w + t1.w);
    *(uint4*)&y[base] = o;
}

// ---------------------------------------------------------------------------
// fp32 -> bf16 elementwise (4/thread).
// ---------------------------------------------------------------------------
__global__ __launch_bounds__(256) void f2bf_kernel(
    const float* __restrict__ in, u16* __restrict__ out)
{
    const int i = blockIdx.x * 256 + threadIdx.x;
    float4 vv = ((const float4*)in)[i];
    f32x4 v; v[0] = vv.x; v[1] = vv.y; v[2] = vv.z; v[3] = vv.w;
    u16x4 o = pack4(v);
    *(u16x4*)&out[(size_t)i * 4] = o;
}

// ---------------------------------------------------------------------------
// Weight transpose-convert: in fp32 [L][K][N] -> out bf16 [L][N][K].
// ---------------------------------------------------------------------------
__global__ __launch_bounds__(256) void wtrans_kernel(
    const float* __restrict__ in, u16* __restrict__ out, int K, int N)
{
    __shared__ float tile[32][33];
    const int l = blockIdx.z;
    in  += (size_t)l * K * N;
    out += (size_t)l * K * N;
    const int n0 = blockIdx.x * 32, k0 = blockIdx.y * 32;
    const int r = threadIdx.x >> 3, c4 = (threadIdx.x & 7) * 4;
    float4 v = *(const float4*)&in[(size_t)(k0 + r) * N + n0 + c4];
    tile[r][c4 + 0] = v.x; tile[r][c4 + 1] = v.y;
    tile[r][c4 + 2] = v.z; tile[r][c4 + 3] = v.w;
    __syncthreads();
    f32x4 t;
    t[0] = tile[c4 + 0][r]; t[1] = tile[c4 + 1][r];
    t[2] = tile[c4 + 2][r]; t[3] = tile[c4 + 3][r];
    st16(&out[(size_t)(n0 + r) * K + k0 + c4], pack4(t));
}

// ---------------------------------------------------------------------------
extern "C" void kernel_launch(void* const* d_in, const int* in_sizes, int n_in,
                              void* d_out, int out_size, void* d_ws, size_t ws_size,
                              hipStream_t stream)
{
    const float* x_in  = (const float*)d_in[0];
    const float* qkv_w = (const float*)d_in[1];
    const float* qkv_b = (const float*)d_in[2];
    const float* ln_g  = (const float*)d_in[3];
    const float* ln_b  = (const float*)d_in[4];
    const float* fc1_w = (const float*)d_in[5];
    const float* fc1_b = (const float*)d_in[6];
    const float* fc2_w = (const float*)d_in[7];
    const float* fc2_b = (const float*)d_in[8];

    float* xbuf = (float*)d_out;   // fp32 working x (B,N,C) — also final out

    // Workspace carve (bytes). Total ≈ 152.7 MB.
    char* p = (char*)d_ws;
    u16* qkv_wt = (u16*)p; p += (size_t)NLAYERS * 1536 * 512 * 2;
    u16* fc1_wt = (u16*)p; p += (size_t)NLAYERS * 1024 * 512 * 2;
    u16* fc2_wt = (u16*)p; p += (size_t)NLAYERS * 512 * 1024 * 2;
    u16* xb = (u16*)p; p += (size_t)ROWS_TOTAL * CH * 2;
    u16* Qb = (u16*)p; p += (size_t)ROWS_TOTAL * CH * 2;
    u16* Kb = (u16*)p; p += (size_t)ROWS_TOTAL * CH * 2;
    u16* Vt = (u16*)p; p += (size_t)ROWS_TOTAL * CH * 2;
    float* rowsum = (float*)p; p += (size_t)ROWS_TOTAL * 4;
    u16* Sb = (u16*)p;                       // attention phase
    u16* yb = Sb;                            // alias: LN out (MLP phase)
    u16* hb = Sb + (size_t)ROWS_TOTAL * CH;  // alias: GELU out (MLP phase)

    const dim3 blk(256);
    const dim3 blk2(512);

    f2bf_kernel<<<dim3(ROWS_TOTAL * CH / 1024), blk, 0, stream>>>(x_in, xb);
    wtrans_kernel<<<dim3(1536 / 32, 512 / 32, NLAYERS), blk, 0, stream>>>(
        qkv_w, qkv_wt, 512, 1536);
    wtrans_kernel<<<dim3(1024 / 32, 512 / 32, NLAYERS), blk, 0, stream>>>(
        fc1_w, fc1_wt, 512, 1024);
    wtrans_kernel<<<dim3(512 / 32, 1024 / 32, NLAYERS), blk, 0, stream>>>(
        fc2_w, fc2_wt, 1024, 512);

    for (int l = 0; l < NLAYERS; ++l) {
        qkv_gemm<<<dim3(128 * 12), blk, 0, stream>>>(
            xb, qkv_wt + (size_t)l * 1536 * 512, qkv_b + (size_t)l * 1536,
            Qb, Kb, Vt, rowsum);
        qk2_gemm<<<dim3(672), blk2, 0, stream>>>(Qb, Kb, Sb, rowsum);
        pv_gemm<<<dim3(512), blk, 0, stream>>>(Sb, Vt, rowsum, xbuf);
        ln_kernel<<<dim3(ROWS_TOTAL / 4), blk, 0, stream>>>(
            xbuf, ln_g + (size_t)l * CH, ln_b + (size_t)l * CH, yb);
        fc1_gemm<<<dim3(128 * 8), blk, 0, stream>>>(
            yb, fc1_wt + (size_t)l * 1024 * 512, fc1_b + (size_t)l * 1024, hb);
        if (l < NLAYERS - 1)
            fc2_gemm<false><<<dim3(128 * 4), blk, 0, stream>>>(
                hb, fc2_wt + (size_t)l * 512 * 1024, fc2_b + (size_t)l * 512,
                xbuf, xb);
        else
            fc2_gemm<true><<<dim3(128 * 4), blk, 0, stream>>>(
                hb, fc2_wt + (size_t)l * 512 * 1024, fc2_b + (size_t)l * 512,
                xbuf, xb);
    }
}